// Round 1
// baseline (334.981 us; speedup 1.0000x reference)
//
#include <hip/hip_runtime.h>

using half8   = __attribute__((ext_vector_type(8))) _Float16;
using floatx4 = __attribute__((ext_vector_type(4))) float;
using floatx2 = __attribute__((ext_vector_type(2))) float;
using short8  = __attribute__((ext_vector_type(8))) short;

// ---- weight repack: qw [co][c][3x3] f32 {-1,0,1} -> wre [s][co][c] f16 ----
__global__ void repack_weights(const float* __restrict__ qw,
                               _Float16* __restrict__ wre, int n) {
  int t = blockIdx.x * 256 + threadIdx.x;
  if (t >= n) return;
  int c = t & 255, co = (t >> 8) & 255, s = t >> 16;
  wre[t] = (_Float16)qw[(co * 256 + c) * 9 + s];
}

// ---- fused conv: stages x (f32 NCHW) -> f16 LDS slot-layout in-kernel ----
// LDS per buffer: [row 4][pos 64][slot 40] f16 (80 B per position).
// pos = w+1 (pos 0 / 57..63 zero pad); rows are padded input rows h0-1..h0+2.
// Block: 256 cout x 112 px (2 out rows x 56). Wave: 64 cout (m=4), j=7 n-tiles.
__global__ __launch_bounds__(256, 2) void binconv_fused(
    const float* __restrict__ x, const float* __restrict__ scale,
    const float* __restrict__ bias, const _Float16* __restrict__ wre,
    float* __restrict__ out)
{
  __shared__ _Float16 xs[2 * 4 * 64 * 40];      // 2 x 20,480 B

  const int tid  = threadIdx.x;
  const int nb   = blockIdx.x;
  const int b    = nb / 28;
  const int h0   = (nb % 28) * 2;
  const int wave = tid >> 6;
  const int lane = tid & 63;
  const int nl   = lane & 15;
  const int quad = lane >> 4;
  const int co_wave = wave * 64;

  // zero both buffers once; pad rows/cols stay zero forever
  {
    short8 z = {0, 0, 0, 0, 0, 0, 0, 0};
    short8* xs8 = reinterpret_cast<short8*>(xs);
#pragma unroll
    for (int i = 0; i < 10; ++i) xs8[tid + i * 256] = z;
  }

  // staging geometry: wave stages padded row r=wave (input row h = h0+wave-1);
  // lane = (channel-pair p, w-quarter wq): 2 channels x 14 w each.
  const int p   = lane & 15;
  const int wq  = lane >> 4;
  const int w0  = wq * 14;
  const int h   = h0 + wave - 1;
  const bool hok = (h >= 0) && (h < 56);
  const float* xca = x + (((size_t)b * 256 + 2 * p) * 56 + (hok ? h : 0)) * 56 + w0;
  const float* xcb = xca + 3136;                // channel +1 (56*56)
  _Float16* const wrow = xs + wave * 2560 + 2 * p;   // + pos*40 (+bufe) later

  floatx2 va[7], vb[7];

  int bbase[7];                                 // byte offsets, 80B/pos stride
#pragma unroll
  for (int j = 0; j < 7; ++j) {
    int n = j * 16 + nl;
    int r = (n >= 56) ? 1 : 0;
    int w = n - r * 56;
    bbase[j] = (r * 64 + w) * 80 + quad * 16;
  }

  const _Float16* aptr[4];
#pragma unroll
  for (int mi = 0; mi < 4; ++mi)
    aptr[mi] = wre + (co_wave + mi * 16 + nl) * 256 + quad * 8;

  floatx4 acc[4][7];
#pragma unroll
  for (int mi = 0; mi < 4; ++mi)
#pragma unroll
    for (int j = 0; j < 7; ++j)
      acc[mi][j] = (floatx4){0.f, 0.f, 0.f, 0.f};

  __syncthreads();                              // zero-fill visible

  // prologue: stage chunk 0 into buf 0
  if (hok) {
#pragma unroll
    for (int i = 0; i < 7; ++i) {
      va[i] = *reinterpret_cast<const floatx2*>(xca + 2 * i);
      vb[i] = *reinterpret_cast<const floatx2*>(xcb + 2 * i);
    }
#pragma unroll
    for (int i = 0; i < 7; ++i) {
      auto u = __builtin_amdgcn_cvt_pkrtz(va[i][0], vb[i][0]);  // (c, c+1) @ w0+2i
      auto v = __builtin_amdgcn_cvt_pkrtz(va[i][1], vb[i][1]);  // (c, c+1) @ w0+2i+1
      *reinterpret_cast<decltype(u)*>(wrow + (w0 + 2 * i + 1) * 40) = u;
      *reinterpret_cast<decltype(v)*>(wrow + (w0 + 2 * i + 2) * 40) = v;
    }
  }

  int bufe = 0;                                 // element offset of current buffer
  for (int cc = 0; cc < 8; ++cc) {
    __syncthreads();                            // chunk cc visible in buf[bufe]
    // T14: issue next chunk's global loads BEFORE the MFMA phase
    if (cc < 7 && hok) {
      const float* A = xca + (size_t)(cc + 1) * 100352;
      const float* B = xcb + (size_t)(cc + 1) * 100352;
#pragma unroll
      for (int i = 0; i < 7; ++i) {
        va[i] = *reinterpret_cast<const floatx2*>(A + 2 * i);
        vb[i] = *reinterpret_cast<const floatx2*>(B + 2 * i);
      }
    }
    const int c0 = cc * 32;
    const char* xb = reinterpret_cast<const char*>(xs) + bufe * 2;
#pragma unroll
    for (int s = 0; s < 9; ++s) {
      const int kh = s / 3, kw = s - kh * 3;
      half8 a[4];
#pragma unroll
      for (int mi = 0; mi < 4; ++mi)
        a[mi] = *reinterpret_cast<const half8*>(aptr[mi] + s * 65536 + c0);
      const int soff = (kh * 64 + kw) * 80;
#pragma unroll
      for (int j = 0; j < 7; ++j) {
        half8 bf = *reinterpret_cast<const half8*>(xb + bbase[j] + soff);
#pragma unroll
        for (int mi = 0; mi < 4; ++mi)
          acc[mi][j] = __builtin_amdgcn_mfma_f32_16x16x32_f16(a[mi], bf, acc[mi][j], 0, 0, 0);
      }
    }
    // cvt + LDS write AFTER compute (loads had the whole MFMA phase in flight);
    // writes go to buf^1, which all waves finished reading before this
    // iteration's barrier -> race-free.
    if (cc < 7 && hok) {
      _Float16* d = wrow + (bufe ^ 10240);
#pragma unroll
      for (int i = 0; i < 7; ++i) {
        auto u = __builtin_amdgcn_cvt_pkrtz(va[i][0], vb[i][0]);
        auto v = __builtin_amdgcn_cvt_pkrtz(va[i][1], vb[i][1]);
        *reinterpret_cast<decltype(u)*>(d + (w0 + 2 * i + 1) * 40) = u;
        *reinterpret_cast<decltype(v)*>(d + (w0 + 2 * i + 2) * 40) = v;
      }
    }
    bufe ^= 10240;
  }

  // epilogue: C/D layout n=lane&15, m=quad*4+reg
#pragma unroll
  for (int mi = 0; mi < 4; ++mi) {
#pragma unroll
    for (int reg = 0; reg < 4; ++reg) {
      int co = co_wave + mi * 16 + quad * 4 + reg;
      float s_ = scale[co];
      float bi = bias[co];
#pragma unroll
      for (int j = 0; j < 7; ++j) {
        int n = j * 16 + nl;
        int r = (n >= 56) ? 1 : 0;
        int w = n - r * 56;
        out[(((size_t)b * 256 + co) * 56 + (h0 + r)) * 56 + w] =
            acc[mi][j][reg] * s_ + bi;
      }
    }
  }
}

extern "C" void kernel_launch(void* const* d_in, const int* in_sizes, int n_in,
                              void* d_out, int out_size, void* d_ws, size_t ws_size,
                              hipStream_t stream) {
  const float* x     = (const float*)d_in[0];   // [32,256,56,56]
  const float* scale = (const float*)d_in[1];   // [256]
  const float* qw    = (const float*)d_in[2];   // [256,256,3,3] in {-1,0,1}
  const float* bias  = (const float*)d_in[3];   // [256]
  float* out = (float*)d_out;

  _Float16* wre = (_Float16*)d_ws;              // 1,179,648 B

  repack_weights<<<2304, 256, 0, stream>>>(qw, wre, 9 * 256 * 256);
  binconv_fused<<<896, 256, 0, stream>>>(x, scale, bias, wre, out);
}

// Round 2
// 323.030 us; speedup vs baseline: 1.0370x; 1.0370x over previous
//
#include <hip/hip_runtime.h>

using half8   = __attribute__((ext_vector_type(8))) _Float16;
using floatx4 = __attribute__((ext_vector_type(4))) float;
using floatx2 = __attribute__((ext_vector_type(2))) float;
using short8  = __attribute__((ext_vector_type(8))) short;

// ---- weight repack: qw [co][c][3x3] f32 {-1,0,1} -> wre [s][co][c] f16 ----
__global__ void repack_weights(const float* __restrict__ qw,
                               _Float16* __restrict__ wre, int n) {
  int t = blockIdx.x * 256 + threadIdx.x;
  if (t >= n) return;
  int c = t & 255, co = (t >> 8) & 255, s = t >> 16;
  wre[t] = (_Float16)qw[(co * 256 + c) * 9 + s];
}

// ---- fused conv, 8-wave / high-occupancy version ----
// LDS per buffer: [row 4][pos 64][slot 40] f16 (80 B per position).
// pos = w+1 (pos 0 / 57..63 zero pad); rows are padded input rows h0-1..h0+2.
// Block: 512 thr = 8 waves. Wave computes 32 cout x 112 px (acc[2][7], 56 AGPR).
// Staging: wave = (row r=wave>>1, channel-half chalf=wave&1);
//          lane = (channel c=lane&15, w-quarter q=lane>>4) -> 14 w of 1 channel.
__global__ __launch_bounds__(512, 4) void binconv_fused(
    const float* __restrict__ x, const float* __restrict__ scale,
    const float* __restrict__ bias, const _Float16* __restrict__ wre,
    float* __restrict__ out)
{
  __shared__ _Float16 xs[2 * 4 * 64 * 40];      // 2 x 20,480 B

  const int tid  = threadIdx.x;
  const int nb   = blockIdx.x;
  const int b    = nb / 28;
  const int h0   = (nb % 28) * 2;
  const int wave = tid >> 6;
  const int lane = tid & 63;
  const int nl   = lane & 15;
  const int quad = lane >> 4;
  const int co_wave = wave * 32;

  // zero both buffers once; pad rows/cols stay zero forever
  {
    short8 z = {0, 0, 0, 0, 0, 0, 0, 0};
    short8* xs8 = reinterpret_cast<short8*>(xs);
#pragma unroll
    for (int i = 0; i < 5; ++i) xs8[tid + i * 512] = z;
  }

  // ---- staging geometry ----
  const int r     = wave >> 1;                  // padded row 0..3
  const int chalf = wave & 1;
  const int sc    = lane & 15;
  const int q     = lane >> 4;
  const int ch    = chalf * 16 + sc;            // channel within 32-chunk
  const int w0    = q * 14;
  const int h     = h0 + r - 1;
  const bool hok  = (h >= 0) && (h < 56);
  const float* xc = x + (((size_t)b * 256 + ch) * 56 + (hok ? h : 0)) * 56 + w0;
  _Float16* const wrow = xs + r * 2560 + ch;    // + (w+1)*40 (+bufe) later

  floatx2 va[7];

  int bbase[7];                                 // byte offsets, 80B/pos stride
#pragma unroll
  for (int j = 0; j < 7; ++j) {
    int n = j * 16 + nl;
    int rr = (n >= 56) ? 1 : 0;
    int w = n - rr * 56;
    bbase[j] = (rr * 64 + w) * 80 + quad * 16;
  }

  const _Float16* aptr[2];
#pragma unroll
  for (int mi = 0; mi < 2; ++mi)
    aptr[mi] = wre + (co_wave + mi * 16 + nl) * 256 + quad * 8;

  floatx4 acc[2][7];
#pragma unroll
  for (int mi = 0; mi < 2; ++mi)
#pragma unroll
    for (int j = 0; j < 7; ++j)
      acc[mi][j] = (floatx4){0.f, 0.f, 0.f, 0.f};

  __syncthreads();                              // zero-fill visible

  // prologue: stage chunk 0 into buf 0
  if (hok) {
#pragma unroll
    for (int i = 0; i < 7; ++i)
      va[i] = *reinterpret_cast<const floatx2*>(xc + 2 * i);
#pragma unroll
    for (int i = 0; i < 7; ++i) {
      wrow[(w0 + 2 * i + 1) * 40] = (_Float16)va[i][0];
      wrow[(w0 + 2 * i + 2) * 40] = (_Float16)va[i][1];
    }
  }

  int bufe = 0;                                 // element offset of current buffer
  for (int cc = 0; cc < 8; ++cc) {
    __syncthreads();                            // chunk cc visible in buf[bufe]
    // T14: issue next chunk's global loads BEFORE the MFMA phase
    if (cc < 7 && hok) {
      const float* A = xc + (size_t)(cc + 1) * 100352;
#pragma unroll
      for (int i = 0; i < 7; ++i)
        va[i] = *reinterpret_cast<const floatx2*>(A + 2 * i);
    }
    const int c0 = cc * 32;
    const char* xb = reinterpret_cast<const char*>(xs) + bufe * 2;
    __builtin_amdgcn_s_setprio(1);
#pragma unroll
    for (int s = 0; s < 9; ++s) {
      const int kh = s / 3, kw = s - kh * 3;
      half8 a[2];
#pragma unroll
      for (int mi = 0; mi < 2; ++mi)
        a[mi] = *reinterpret_cast<const half8*>(aptr[mi] + s * 65536 + c0);
      const int soff = (kh * 64 + kw) * 80;
#pragma unroll
      for (int j = 0; j < 7; ++j) {
        half8 bf = *reinterpret_cast<const half8*>(xb + bbase[j] + soff);
#pragma unroll
        for (int mi = 0; mi < 2; ++mi)
          acc[mi][j] = __builtin_amdgcn_mfma_f32_16x16x32_f16(a[mi], bf, acc[mi][j], 0, 0, 0);
      }
    }
    __builtin_amdgcn_s_setprio(0);
    // cvt + LDS write AFTER compute (loads had the whole MFMA phase in flight);
    // writes go to buf^1, which all waves finished reading before this
    // iteration's barrier -> race-free.
    if (cc < 7 && hok) {
      _Float16* d = wrow + (bufe ^ 10240);
#pragma unroll
      for (int i = 0; i < 7; ++i) {
        d[(w0 + 2 * i + 1) * 40] = (_Float16)va[i][0];
        d[(w0 + 2 * i + 2) * 40] = (_Float16)va[i][1];
      }
    }
    bufe ^= 10240;
  }

  // epilogue: C/D layout n=lane&15, m=quad*4+reg
#pragma unroll
  for (int mi = 0; mi < 2; ++mi) {
#pragma unroll
    for (int reg = 0; reg < 4; ++reg) {
      int co = co_wave + mi * 16 + quad * 4 + reg;
      float s_ = scale[co];
      float bi = bias[co];
#pragma unroll
      for (int j = 0; j < 7; ++j) {
        int n = j * 16 + nl;
        int rr = (n >= 56) ? 1 : 0;
        int w = n - rr * 56;
        out[(((size_t)b * 256 + co) * 56 + (h0 + rr)) * 56 + w] =
            acc[mi][j][reg] * s_ + bi;
      }
    }
  }
}

extern "C" void kernel_launch(void* const* d_in, const int* in_sizes, int n_in,
                              void* d_out, int out_size, void* d_ws, size_t ws_size,
                              hipStream_t stream) {
  const float* x     = (const float*)d_in[0];   // [32,256,56,56]
  const float* scale = (const float*)d_in[1];   // [256]
  const float* qw    = (const float*)d_in[2];   // [256,256,3,3] in {-1,0,1}
  const float* bias  = (const float*)d_in[3];   // [256]
  float* out = (float*)d_out;

  _Float16* wre = (_Float16*)d_ws;              // 1,179,648 B

  repack_weights<<<2304, 256, 0, stream>>>(qw, wre, 9 * 256 * 256);
  binconv_fused<<<896, 512, 0, stream>>>(x, scale, bias, wre, out);
}